// Round 5
// baseline (312.727 us; speedup 1.0000x reference)
//
#include <hip/hip_runtime.h>

typedef unsigned short u16;
typedef unsigned int u32;
typedef __bf16 bf16x8 __attribute__((ext_vector_type(8)));
typedef short s16x4 __attribute__((ext_vector_type(4)));
typedef float f32x4 __attribute__((ext_vector_type(4)));

#define AS1(p) ((const __attribute__((address_space(1))) void*)(p))
#define AS3(p) ((__attribute__((address_space(3))) void*)(p))

#if __has_builtin(__builtin_amdgcn_exp2f)
#define EXP2(x) __builtin_amdgcn_exp2f(x)
#else
#define EXP2(x) __builtin_exp2f(x)
#endif

__device__ __forceinline__ u16 f2bf(float f) {
    u32 u = __float_as_uint(f);
    u += 0x7fffu + ((u >> 16) & 1u);   // round-to-nearest-even
    return (u16)(u >> 16);
}

__device__ __forceinline__ short bfbits(float f) {
    __bf16 h = (__bf16)f;
    return __builtin_bit_cast(short, h);
}

// Q/K/V/O buffers are each 24*4096*64 = 6291456 elements
#define NXQ 6291456
// Q scale: 1/sqrt(64) * log2(e), folded into Q projection so flash uses exp2
#define QSCALE 0.1803368801111249f

// ---------------- prep: x cast + 4x W transpose (bf16) + bias fuse ----------------
__global__ __launch_bounds__(256) void prep_kernel(
    const float* __restrict__ x,
    const float* __restrict__ wq, const float* __restrict__ wk,
    const float* __restrict__ wv, const float* __restrict__ wo,
    const float* __restrict__ bq, const float* __restrict__ bk,
    const float* __restrict__ bv,
    u16* __restrict__ xbf, u16* __restrict__ WT, float* __restrict__ bqkv)
{
    const int t = threadIdx.x;
    const int bid = blockIdx.x;
    if (bid < 6144) {                     // x: 8192*768 fp32 -> bf16
        int i = bid * 256 + t;
        float4 v = ((const float4*)x)[i];
        uint2 o;
        o.x = (u32)f2bf(v.x) | ((u32)f2bf(v.y) << 16);
        o.y = (u32)f2bf(v.z) | ((u32)f2bf(v.w) << 16);
        ((uint2*)xbf)[i] = o;
        return;
    }
    int tb = bid - 6144;                  // 0..575
    int mat = tb / 144;
    int tt = tb - mat * 144;
    int tr = tt / 12, tc = tt - tr * 12;
    const float* W = (mat == 0) ? wq : (mat == 1) ? wk : (mat == 2) ? wv : wo;
    __shared__ u16 sT[64 * 72];
    #pragma unroll
    for (int rr = 0; rr < 4; ++rr) {
        int r = (t >> 4) + rr * 16;
        int cb = (t & 15) * 4;
        float4 v = *(const float4*)&W[(size_t)(tr * 64 + r) * 768 + tc * 64 + cb];
        sT[(cb + 0) * 72 + r] = f2bf(v.x);
        sT[(cb + 1) * 72 + r] = f2bf(v.y);
        sT[(cb + 2) * 72 + r] = f2bf(v.z);
        sT[(cb + 3) * 72 + r] = f2bf(v.w);
    }
    __syncthreads();
    #pragma unroll
    for (int i = 0; i < 2; ++i) {
        int nr = t >> 2;
        int cc = (t & 3) * 16 + i * 8;
        *(uint4*)&WT[(size_t)(mat * 768 + tc * 64 + nr) * 768 + tr * 64 + cc] =
            *(uint4*)&sT[nr * 72 + cc];
    }
    if (tb < 9) {
        int i = tb * 256 + t;
        if (i < 2304)
            bqkv[i] = (i < 768) ? bq[i] : (i < 1536) ? bk[i - 768] : bv[i - 1536];
    }
}

// ---------------- QKV GEMM: BK=32 double-buffered DMA pipeline ----------------
__global__ __launch_bounds__(256, 4) void gemm_qkv(
    const u16* __restrict__ A, const u16* __restrict__ WT,
    const float* __restrict__ bias, u16* __restrict__ out)
{
    __shared__ u16 sA[2][128 * 32];
    __shared__ u16 sB[2][128 * 32];
    const int m0 = blockIdx.x * 128;
    const int n0g = blockIdx.y * 128;
    const int tid = threadIdx.x, lane = tid & 63, wave = tid >> 6;
    const int quad = lane >> 4, l16 = lane & 15;
    const int wm = (wave & 1) * 64, wn = (wave >> 1) * 64;

    f32x4 acc[4][4];
    #pragma unroll
    for (int i = 0; i < 4; ++i)
        #pragma unroll
        for (int j = 0; j < 4; ++j)
            #pragma unroll
            for (int r = 0; r < 4; ++r)
                acc[i][j][r] = 0.f;

    const int srow = lane >> 2;          // row within 16-row chunk
    const int scc = lane & 3;            // k-chunk (8 u16)

    auto stage = [&](int k0, int buf) {
        #pragma unroll
        for (int i = 0; i < 2; ++i) {
            int c = wave * 2 + i;
            int row = c * 16 + srow;
            int kc = (scc ^ (row & 3)) * 8;
            __builtin_amdgcn_global_load_lds(
                AS1(&A[(size_t)(m0 + row) * 768 + k0 + kc]),
                AS3(&sA[buf][c * 512]), 16, 0, 0);
            __builtin_amdgcn_global_load_lds(
                AS1(&WT[(size_t)(n0g + row) * 768 + k0 + kc]),
                AS3(&sB[buf][c * 512]), 16, 0, 0);
        }
    };

    auto compute = [&](int buf) {
        bf16x8 af[4], bfr[4];
        #pragma unroll
        for (int i = 0; i < 4; ++i) {
            int row = wm + i * 16 + l16;
            af[i] = *(const bf16x8*)&sA[buf][row * 32 + ((quad ^ (row & 3)) * 8)];
        }
        #pragma unroll
        for (int j = 0; j < 4; ++j) {
            int row = wn + j * 16 + l16;
            bfr[j] = *(const bf16x8*)&sB[buf][row * 32 + ((quad ^ (row & 3)) * 8)];
        }
        #pragma unroll
        for (int i = 0; i < 4; ++i)
            #pragma unroll
            for (int j = 0; j < 4; ++j)
                acc[i][j] = __builtin_amdgcn_mfma_f32_16x16x32_bf16(af[i], bfr[j], acc[i][j], 0, 0, 0);
    };

    stage(0, 0);
    for (int kt = 0; kt < 24; kt += 2) {
        __syncthreads();
        stage((kt + 1) * 32, 1);
        compute(0);
        __syncthreads();
        if (kt + 2 < 24) stage((kt + 2) * 32, 0);
        compute(1);
    }

    const int mat = blockIdx.y / 6;
    const int nm0 = n0g - mat * 768;
    const float scale = (mat == 0) ? QSCALE : 1.0f;
    u16* dst = out + (size_t)mat * NXQ;
    #pragma unroll
    for (int i = 0; i < 4; ++i) {
        #pragma unroll
        for (int j = 0; j < 4; ++j) {
            int colg = n0g + wn + j * 16 + l16;
            int col = nm0 + wn + j * 16 + l16;
            float bv = bias[colg];
            int h = col >> 6, d = col & 63;
            int row0 = m0 + wm + i * 16 + quad * 4;
            int b = row0 >> 12, s = row0 & 4095;
            if (mat < 2) {
                #pragma unroll
                for (int r = 0; r < 4; ++r)
                    dst[(((size_t)(b * 12 + h) * 4096) + s + r) * 64 + d] =
                        f2bf((acc[i][j][r] + bv) * scale);
            } else {
                ushort4 w;
                w.x = f2bf(acc[i][j][0] + bv);
                w.y = f2bf(acc[i][j][1] + bv);
                w.z = f2bf(acc[i][j][2] + bv);
                w.w = f2bf(acc[i][j][3] + bv);
                *(ushort4*)&dst[(((size_t)(b * 12 + h) * 64 + d) * 4096) + s] = w;
            }
        }
    }
}

// ---------------- out-proj GEMM: 64x128 tile, BK=32 dbuf, grid 768 ----------------
__global__ __launch_bounds__(256, 4) void gemm_out(
    const u16* __restrict__ A, const u16* __restrict__ WT,
    const float* __restrict__ bias, float* __restrict__ out)
{
    __shared__ u16 sA[2][64 * 32];
    __shared__ u16 sB[2][128 * 32];
    const int m0 = blockIdx.x * 64;
    const int n0 = blockIdx.y * 128;
    const int tid = threadIdx.x, lane = tid & 63, wave = tid >> 6;
    const int quad = lane >> 4, l16 = lane & 15;
    const int wm = (wave & 1) * 32, wn = (wave >> 1) * 64;

    f32x4 acc[2][4];
    #pragma unroll
    for (int i = 0; i < 2; ++i)
        #pragma unroll
        for (int j = 0; j < 4; ++j)
            #pragma unroll
            for (int r = 0; r < 4; ++r)
                acc[i][j][r] = 0.f;

    const int srow = lane >> 2;
    const int scc = lane & 3;

    auto stage = [&](int k0, int buf) {
        {
            int row = wave * 16 + srow;
            int kc = (scc ^ (row & 3)) * 8;
            __builtin_amdgcn_global_load_lds(
                AS1(&A[(size_t)(m0 + row) * 768 + k0 + kc]),
                AS3(&sA[buf][wave * 512]), 16, 0, 0);
        }
        #pragma unroll
        for (int i = 0; i < 2; ++i) {
            int c = wave * 2 + i;
            int row = c * 16 + srow;
            int kc = (scc ^ (row & 3)) * 8;
            __builtin_amdgcn_global_load_lds(
                AS1(&WT[(size_t)(n0 + row) * 768 + k0 + kc]),
                AS3(&sB[buf][c * 512]), 16, 0, 0);
        }
    };

    auto compute = [&](int buf) {
        bf16x8 af[2], bfr[4];
        #pragma unroll
        for (int i = 0; i < 2; ++i) {
            int row = wm + i * 16 + l16;
            af[i] = *(const bf16x8*)&sA[buf][row * 32 + ((quad ^ (row & 3)) * 8)];
        }
        #pragma unroll
        for (int j = 0; j < 4; ++j) {
            int row = wn + j * 16 + l16;
            bfr[j] = *(const bf16x8*)&sB[buf][row * 32 + ((quad ^ (row & 3)) * 8)];
        }
        #pragma unroll
        for (int i = 0; i < 2; ++i)
            #pragma unroll
            for (int j = 0; j < 4; ++j)
                acc[i][j] = __builtin_amdgcn_mfma_f32_16x16x32_bf16(af[i], bfr[j], acc[i][j], 0, 0, 0);
    };

    stage(0, 0);
    for (int kt = 0; kt < 24; kt += 2) {
        __syncthreads();
        stage((kt + 1) * 32, 1);
        compute(0);
        __syncthreads();
        if (kt + 2 < 24) stage((kt + 2) * 32, 0);
        compute(1);
    }

    #pragma unroll
    for (int i = 0; i < 2; ++i) {
        #pragma unroll
        for (int j = 0; j < 4; ++j) {
            int col = n0 + wn + j * 16 + l16;
            float bv = bias[col];
            #pragma unroll
            for (int r = 0; r < 4; ++r) {
                int row = m0 + wm + i * 16 + quad * 4 + r;
                out[(size_t)row * 768 + col] = acc[i][j][r] + bv;
            }
        }
    }
}

// ---------------- flash attention: 64 q-rows/block (4 waves x 16), 5 blocks/CU ----
// Q pre-scaled by QSCALE -> p = exp2(score). Row-sums l via all-ones MFMA A-frag.
__global__ __launch_bounds__(256, 5) void flash_kernel(
    const u16* __restrict__ Q, const u16* __restrict__ K,
    const u16* __restrict__ Vt, u16* __restrict__ O)
{
    const int bh = blockIdx.y;
    const int q0 = blockIdx.x * 64;
    const u16* Qp = Q + (size_t)bh * 4096 * 64;
    const u16* Kp = K + (size_t)bh * 4096 * 64;
    const u16* Vp = Vt + (size_t)bh * 64 * 4096;
    const int tid = threadIdx.x, lane = tid & 63, wave = tid >> 6;
    const int quad = lane >> 4, l16 = lane & 15;

    __shared__ u16 sK[2][64 * 64];    // [key][d], XOR-swizzled chunks
    __shared__ u16 sVT[2][64 * 64];   // [d][key]

    // wave owns 16 q rows; B-operand fragments held in registers
    const int qrow = q0 + wave * 16;
    bf16x8 qf[2];
    #pragma unroll
    for (int s = 0; s < 2; ++s)
        qf[s] = *(const bf16x8*)&Qp[(size_t)(qrow + l16) * 64 + s * 32 + quad * 8];

    f32x4 oacc[4];   // O^T: [d-subtile jd], cols = 16 q
    f32x4 lacc;
    #pragma unroll
    for (int jd = 0; jd < 4; ++jd)
        #pragma unroll
        for (int r = 0; r < 4; ++r)
            oacc[jd][r] = 0.f;
    #pragma unroll
    for (int r = 0; r < 4; ++r)
        lacc[r] = 0.f;

    s16x4 ones;   // bf16 1.0 x4 : all-ones 16x16 A-operand (lane-invariant)
    #pragma unroll
    for (int r = 0; r < 4; ++r) ones[r] = (short)0x3F80;

    const int srow = lane >> 3;
    auto stage = [&](int t, int buf) {
        #pragma unroll
        for (int i = 0; i < 2; ++i) {
            int c = wave * 2 + i;
            int row = c * 8 + srow;
            int kc = ((lane & 7) ^ (row & 7)) * 8;
            __builtin_amdgcn_global_load_lds(
                AS1(&Kp[(size_t)(t * 64 + row) * 64 + kc]),
                AS3(&sK[buf][c * 512]), 16, 0, 0);
            __builtin_amdgcn_global_load_lds(
                AS1(&Vp[(size_t)row * 4096 + t * 64 + kc]),
                AS3(&sVT[buf][c * 512]), 16, 0, 0);
        }
    };

    auto body = [&](int cur) {
        // S^T = K @ Q^T : 64 keys x 16 q
        f32x4 sacc[4];
        #pragma unroll
        for (int m = 0; m < 4; ++m)
            #pragma unroll
            for (int r = 0; r < 4; ++r)
                sacc[m][r] = 0.f;
        #pragma unroll
        for (int s = 0; s < 2; ++s) {
            bf16x8 ak[4];
            #pragma unroll
            for (int m = 0; m < 4; ++m) {
                int row = m * 16 + l16;
                ak[m] = *(const bf16x8*)&sK[cur][row * 64 + (((s * 4 + quad) ^ (row & 7)) * 8)];
            }
            #pragma unroll
            for (int m = 0; m < 4; ++m)
                sacc[m] = __builtin_amdgcn_mfma_f32_16x16x32_bf16(ak[m], qf[s], sacc[m], 0, 0, 0);
        }

        // p = exp2(score); pack P^T (C-layout == B-frag of 16x16x16)
        s16x4 bp[4];
        #pragma unroll
        for (int kk = 0; kk < 4; ++kk) {
            s16x4 b;
            b[0] = bfbits(EXP2(sacc[kk][0]));
            b[1] = bfbits(EXP2(sacc[kk][1]));
            b[2] = bfbits(EXP2(sacc[kk][2]));
            b[3] = bfbits(EXP2(sacc[kk][3]));
            bp[kk] = b;
        }

        // O^T += V^T @ P^T; l += 1^T @ P^T (ones A-frag, no LDS)
        #pragma unroll
        for (int kk = 0; kk < 4; ++kk) {
            s16x4 av[4];
            #pragma unroll
            for (int jd = 0; jd < 4; ++jd) {
                int row = jd * 16 + l16;
                av[jd] = *(const s16x4*)&sVT[cur][row * 64 +
                            (((kk * 2 + (quad >> 1)) ^ (row & 7)) * 8) + (quad & 1) * 4];
            }
            #pragma unroll
            for (int jd = 0; jd < 4; ++jd)
                oacc[jd] = __builtin_amdgcn_mfma_f32_16x16x16bf16_1k(av[jd], bp[kk], oacc[jd], 0, 0, 0);
            lacc = __builtin_amdgcn_mfma_f32_16x16x16bf16_1k(ones, bp[kk], lacc, 0, 0, 0);
        }
    };

    stage(0, 0);
    for (int t = 0; t < 64; t += 2) {
        __syncthreads();
        stage(t + 1, 1);
        body(0);
        __syncthreads();
        if (t + 2 < 64) stage(t + 2, 0);
        body(1);
    }

    const int b = bh / 12, h = bh - b * 12;
    float inv = 1.0f / lacc[0];   // every C row of ones-MFMA holds the column sum
    int s = qrow + l16;
    #pragma unroll
    for (int jd = 0; jd < 4; ++jd) {
        ushort4 w;
        w.x = f2bf(oacc[jd][0] * inv);
        w.y = f2bf(oacc[jd][1] * inv);
        w.z = f2bf(oacc[jd][2] * inv);
        w.w = f2bf(oacc[jd][3] * inv);
        *(ushort4*)&O[((size_t)(b * 4096 + s)) * 768 + h * 64 + jd * 16 + quad * 4] = w;
    }
}

extern "C" void kernel_launch(void* const* d_in, const int* in_sizes, int n_in,
                              void* d_out, int out_size, void* d_ws, size_t ws_size,
                              hipStream_t stream)
{
    (void)in_sizes; (void)n_in; (void)out_size; (void)ws_size;
    const float* x  = (const float*)d_in[0];
    const float* wq = (const float*)d_in[1];
    const float* bq = (const float*)d_in[2];
    const float* wk = (const float*)d_in[3];
    const float* bk = (const float*)d_in[4];
    const float* wv = (const float*)d_in[5];
    const float* bv = (const float*)d_in[6];
    const float* wo = (const float*)d_in[7];
    const float* bo = (const float*)d_in[8];
    float* out = (float*)d_out;

    u16* ws = (u16*)d_ws;
    u16* xbf = ws;                          // 8192*768
    u16* WT  = xbf + (size_t)8192 * 768;    // 3072*768 (WqT|WkT|WvT|WoT)
    u16* Qb  = WT + (size_t)3072 * 768;     // NXQ each
    u16* Kb  = Qb + NXQ;
    u16* Vtb = Kb + NXQ;
    u16* Ob  = Vtb + NXQ;
    float* bqkv = (float*)(Ob + NXQ);       // 2304 fp32

    prep_kernel<<<6720, 256, 0, stream>>>(x, wq, wk, wv, wo, bq, bk, bv, xbf, WT, bqkv);
    gemm_qkv<<<dim3(64, 18), 256, 0, stream>>>(xbf, WT, bqkv, Qb);
    flash_kernel<<<dim3(64, 24), 256, 0, stream>>>(Qb, Kb, Vtb, Ob);
    gemm_out<<<dim3(128, 6), 256, 0, stream>>>(Ob, WT + (size_t)2304 * 768, bo, out);
}